// Round 7
// baseline (228.026 us; speedup 1.0000x reference)
//
#include <hip/hip_runtime.h>

#define KORD   10
#define MAXDEG 64
#define NB     2048        // nodes per graph
#define NROWS  16384       // 8 * 2048
#define HD     256         // hidden per conv
#define XBW    1536        // XB width: [x(768) | h0(256) | h1(256) | h2(256)]

typedef __attribute__((ext_vector_type(8))) short short8;
typedef __attribute__((ext_vector_type(4))) float f32x4;

__device__ inline unsigned short f2bf(float f) {
  union { float f; unsigned u; } v; v.f = f;
  unsigned r = v.u + 0x7fff + ((v.u >> 16) & 1);   // round-to-nearest-even
  return (unsigned short)(r >> 16);
}
__device__ inline float bf2f(unsigned short b) {
  union { unsigned u; float f; } v; v.u = ((unsigned)b) << 16;
  return v.f;
}

#define AS1 __attribute__((address_space(1)))
#define AS3 __attribute__((address_space(3)))
__device__ inline void gload16(const void* g, void* l) {
  __builtin_amdgcn_global_load_lds((const AS1 void*)g, (AS3 void*)l, 16, 0, 0);
}

// ---------------------------------------------------------------------------
__device__ inline double binom_d(int n, int r) {
  if (r < 0 || r > n) return 0.0;
  double v = 1.0;
  for (int i = 1; i <= r; ++i) v = v * (double)(n - r + i) / (double)i;
  return v;
}

// ---------------------------------------------------------------------------
// q[m] = [z^m] sum_k relu(coe[k]) * C(K,k)/2^K * (1-z)^k (1+z)^{K-k}
// zstate[m] = 1 iff q[j]==0 for all j>=m. Exact in fp64 for dyadic coe.
// Also builds biasX[768] = [b0 | 0 | 0] (bias for the wide x-GEMM).
// ---------------------------------------------------------------------------
__global__ __launch_bounds__(128) void qz_kernel(const float* __restrict__ coe,
                                                 const float* __restrict__ b0,
                                                 float* __restrict__ qf,
                                                 int* __restrict__ zstate,
                                                 float* __restrict__ biasX) {
  __shared__ double part[(KORD + 1) * (KORD + 1)];   // [k][m]
  __shared__ double qs[KORD + 1];
  const int t = threadIdx.x;
  for (int i = t; i < 768; i += 128) biasX[i] = i < 256 ? b0[i] : 0.0f;
  if (t < (KORD + 1) * (KORD + 1)) {
    const int k = t / (KORD + 1), m = t % (KORD + 1);
    double tt = (double)coe[k];
    if (tt < 0.0) tt = 0.0;                          // relu(coe)
    const double ck = tt * binom_d(KORD, k) / 1024.0;
    double s = 0.0;
    for (int j = 0; j <= k && j <= m; ++j) {
      const int rem = m - j;
      if (rem <= KORD - k) {
        const double term = binom_d(k, j) * binom_d(KORD - k, rem);
        s += (j & 1) ? -term : term;
      }
    }
    part[t] = ck * s;
  }
  __syncthreads();
  if (t <= KORD) {
    double q = 0.0;
    for (int k = 0; k <= KORD; ++k) q += part[k * (KORD + 1) + t];
    qs[t] = q;
    qf[t] = (float)q;
  }
  __syncthreads();
  if (t == 0) {
    zstate[KORD + 1] = 1;
    int z = 1;
    for (int m = KORD; m >= 0; --m) {
      if (qs[m] != 0.0) z = 0;
      zstate[m] = z;
    }
  }
}

// ---------------------------------------------------------------------------
// Fused prep: one dispatch, branch by block range.
//   [0,4096)      build_adj (runtime-dead when zstate[1] -> early exit)
//   [4096,6144)   xcvt: x fp32 -> XB bf16 cols [0,768)
//   [6144,8064)   wcvt x7 jobs -> WtX / WtB1 / WtB2 / WtO (bf16, transposed)
// ---------------------------------------------------------------------------
__global__ __launch_bounds__(256) void prep_kernel(
    const float* __restrict__ adj, const float* __restrict__ x,
    const float* __restrict__ W0, const float* __restrict__ W1,
    const float* __restrict__ W2, const float* __restrict__ Wout,
    const int* __restrict__ zstate,
    int* __restrict__ cnt, float* __restrict__ dis,
    unsigned short* __restrict__ colidx,
    unsigned short* __restrict__ XB,
    unsigned short* __restrict__ WtX, unsigned short* __restrict__ WtB1,
    unsigned short* __restrict__ WtB2, unsigned short* __restrict__ WtO) {
  __shared__ float tile[32][33];
  const int blk = blockIdx.x;
  const int t = threadIdx.x;

  if (blk < 4096) {                       // ---- build_adj ----
    if (zstate[1]) return;                // outputs never consumed: skip
    const int wave = t >> 6;
    const int lane = t & 63;
    const int row  = blk * 4 + wave;
    const float4* arow4 = (const float4*)(adj + (size_t)row * NB);
    unsigned short* ci = colidx + (size_t)row * MAXDEG;
    float4 v[8];
#pragma unroll
    for (int i = 0; i < 8; ++i) v[i] = arow4[i * 64 + lane];
    const unsigned long long lower = (1ull << lane) - 1ull;
    int base = 0;
#pragma unroll
    for (int i = 0; i < 8; ++i) {
      const int col = i * 256 + lane * 4;
      const int b0 = v[i].x > 0.f, b1 = v[i].y > 0.f;
      const int b2 = v[i].z > 0.f, b3 = v[i].w > 0.f;
      const unsigned long long m0 = __ballot(b0), m1 = __ballot(b1);
      const unsigned long long m2 = __ballot(b2), m3 = __ballot(b3);
      int pre = base + __popcll(m0 & lower) + __popcll(m1 & lower) +
                __popcll(m2 & lower) + __popcll(m3 & lower);
      if (b0) { if (pre < MAXDEG) ci[pre] = (unsigned short)col; ++pre; }
      if (b1) { if (pre < MAXDEG) ci[pre] = (unsigned short)(col + 1); ++pre; }
      if (b2) { if (pre < MAXDEG) ci[pre] = (unsigned short)(col + 2); ++pre; }
      if (b3) { if (pre < MAXDEG) ci[pre] = (unsigned short)(col + 3); ++pre; }
      base += __popcll(m0) + __popcll(m1) + __popcll(m2) + __popcll(m3);
    }
    if (lane == 0) {
      cnt[row] = base > MAXDEG ? MAXDEG : base;
      dis[row] = base > 0 ? rsqrtf((float)base) : 0.0f;
    }
    return;
  }

  if (blk < 6144) {                       // ---- xcvt: 8 rows per block ----
    const int r0 = (blk - 4096) * 8;
    for (int i = t; i < 8 * 192; i += 256) {
      const int r = r0 + (i / 192);
      const int c = (i % 192) * 4;
      float4 v = *(const float4*)&x[(size_t)r * 768 + c];
      union { unsigned short s[4]; uint2 u; } o;
      o.s[0] = f2bf(v.x); o.s[1] = f2bf(v.y);
      o.s[2] = f2bf(v.z); o.s[3] = f2bf(v.w);
      *(uint2*)&XB[(size_t)r * XBW + c] = o.u;
    }
    return;
  }

  // ---- wcvt: W[k][n] (N cols) -> Wt[(noff+n)*ldt + koff + k] ----
  const float* W; unsigned short* Wt; int N, ldt, koff, noff, gx, lb;
  int b = blk - 6144;
  if (b < 192)       { W = W0;             Wt = WtX;  N = 256; ldt = 768;  koff = 0;   noff = 0;   gx = 24; lb = b; }
  else if (b < 384)  { W = W1;             Wt = WtX;  N = 256; ldt = 768;  koff = 0;   noff = 256; gx = 24; lb = b - 192; }
  else if (b < 576)  { W = W2;             Wt = WtX;  N = 256; ldt = 768;  koff = 0;   noff = 512; gx = 24; lb = b - 384; }
  else if (b < 640)  { W = W1 + 768 * 256; Wt = WtB1; N = 256; ldt = 256;  koff = 0;   noff = 0;   gx = 8;  lb = b - 576; }
  else if (b < 768)  { W = W2 + 768 * 256; Wt = WtB2; N = 256; ldt = 512;  koff = 0;   noff = 0;   gx = 16; lb = b - 640; }
  else if (b < 1344) { W = Wout;           Wt = WtO;  N = 768; ldt = 1536; koff = 0;   noff = 0;   gx = 24; lb = b - 768; }
  else               { W = Wout;           Wt = WtO;  N = 768; ldt = 1536; koff = 768; noff = 0;   gx = 24; lb = b - 1344; }
  const int k0 = (lb % gx) * 32, n0 = (lb / gx) * 32;
  const int tx = t & 31, ty = t >> 5;
#pragma unroll
  for (int i = 0; i < 4; ++i)
    tile[ty + 8 * i][tx] = W[(size_t)(k0 + ty + 8 * i) * N + n0 + tx];
  __syncthreads();
#pragma unroll
  for (int i = 0; i < 4; ++i)
    Wt[(size_t)(noff + n0 + ty + 8 * i) * ldt + koff + k0 + tx] =
        f2bf(tile[tx][ty + 8 * i]);
}

// ---------------------------------------------------------------------------
// bf16 MFMA GEMM: out[M=16384, N] = A[M,Kd] @ Wt[N,Kd]^T + bias (+ Cin)
// BM=BN=128, BK=32, 4 waves, 4-buffer LDS ring, counted vmcnt, raw s_barrier.
// Epilogue column split: col >= pxsplit  -> px (bf16 partial buffer, always)
//   else zstate[1]&&xb_epi -> fused fast-Horner: relu(q0*v) -> XB (+bern)
//   else outB (bf16) / outF (fp32).
// Cin (bf16, nullable): epilogue C-initializer (x-partial from wide GEMM).
// ---------------------------------------------------------------------------
__global__ __launch_bounds__(256) void mfma_gemm_kernel(
    int Kd,
    const unsigned short* __restrict__ A, int lda,
    const unsigned short* __restrict__ Wt, int ldw,
    const float* __restrict__ bias,
    const unsigned short* __restrict__ Cin, int ldc,
    unsigned short* __restrict__ px, int ldpx, int pxsplit,
    float* __restrict__ outF, unsigned short* __restrict__ outB, int ldo,
    const float* __restrict__ qf, const int* __restrict__ zstate,
    unsigned short* __restrict__ xb_epi, unsigned short* __restrict__ bern_epi,
    int layer) {
  __shared__ __align__(16) unsigned short Asl[4][128 * 32];
  __shared__ __align__(16) unsigned short Bsl[4][128 * 32];
  const int t    = threadIdx.x;
  const int lane = t & 63;
  const int wid  = t >> 6;
  const int wr   = wid >> 1, wc = wid & 1;

  const int gx  = gridDim.x;
  const int nwg = gx * gridDim.y;
  int bid = blockIdx.y * gx + blockIdx.x;
  if ((nwg & 7) == 0) bid = (bid & 7) * (nwg >> 3) + (bid >> 3);
  const int row0 = (bid / gx) * 128;
  const int col0 = (bid % gx) * 128;

  f32x4 acc[4][4] = {};

  const int swz    = ((lane & 3) ^ ((lane >> 3) & 3)) * 8;
  const int subrow = lane >> 2;
  const int fr = lane & 15;
  const int fq = lane >> 4;

  const int nkt = Kd >> 5;

  auto stage = [&](int kt, int pb) {
    const int kbase = kt << 5;
#pragma unroll
    for (int i = 0; i < 4; ++i) {
      const int c = wid * 4 + i;                 // 0..15; <8 = A, else B
      if (c < 8) {
        const int r = row0 + c * 16 + subrow;
        gload16(A + (size_t)r * lda + kbase + swz, &Asl[pb][c * 512]);
      } else {
        const int cc = c - 8;
        const int r = col0 + cc * 16 + subrow;
        gload16(Wt + (size_t)r * ldw + kbase + swz, &Bsl[pb][cc * 512]);
      }
    }
  };

  stage(0, 0);
  if (nkt > 1) stage(1, 1);

  for (int kt = 0; kt < nkt; ++kt) {
    const int pb = kt & 3;
    if (kt + 2 < nkt) {
      stage(kt + 2, (kt + 2) & 3);
      asm volatile("s_waitcnt vmcnt(8)" ::: "memory");
    } else if (kt + 1 < nkt) {
      asm volatile("s_waitcnt vmcnt(4)" ::: "memory");
    } else {
      asm volatile("s_waitcnt vmcnt(0)" ::: "memory");
    }
    __builtin_amdgcn_s_barrier();
    asm volatile("" ::: "memory");

    short8 af[4], bfr[4];
#pragma unroll
    for (int m = 0; m < 4; ++m) {
      const int r = wr * 64 + m * 16 + fr;
      const int colb = (fq * 16) ^ (((r >> 1) & 3) << 4);
      af[m] = *(const short8*)((const char*)&Asl[pb][0] + r * 64 + colb);
    }
#pragma unroll
    for (int n = 0; n < 4; ++n) {
      const int r = wc * 64 + n * 16 + fr;
      const int colb = (fq * 16) ^ (((r >> 1) & 3) << 4);
      bfr[n] = *(const short8*)((const char*)&Bsl[pb][0] + r * 64 + colb);
    }
    __builtin_amdgcn_s_setprio(1);
#pragma unroll
    for (int m = 0; m < 4; ++m)
#pragma unroll
      for (int n = 0; n < 4; ++n)
        acc[m][n] = __builtin_amdgcn_mfma_f32_16x16x32_bf16(af[m], bfr[n],
                                                            acc[m][n], 0, 0, 0);
    __builtin_amdgcn_s_setprio(0);
  }

  // epilogue: C/D layout col = lane&15, row = (lane>>4)*4 + reg
  int fastepi = 0; float q0 = 0.f;
  if (xb_epi) { fastepi = zstate[1]; q0 = qf[0]; }
#pragma unroll
  for (int n = 0; n < 4; ++n) {
    const int col = col0 + wc * 64 + n * 16 + fr;
    const float bv = bias[col];
#pragma unroll
    for (int m = 0; m < 4; ++m) {
      const int rbase = row0 + wr * 64 + m * 16 + fq * 4;
#pragma unroll
      for (int r = 0; r < 4; ++r) {
        float v = acc[m][n][r] + bv;
        const size_t rr = (size_t)(rbase + r);
        if (Cin) v += bf2f(Cin[rr * ldc + col]);
        if (col >= pxsplit) {
          px[rr * ldpx + (col - pxsplit)] = f2bf(v);
        } else if (fastepi) {
          const float hv = fmaxf(q0 * v, 0.f);
          const unsigned short hb = f2bf(hv);
          xb_epi[rr * XBW + 768 + layer * HD + col] = hb;
          if (bern_epi)
            bern_epi[rr * 768 + layer * HD + col] =
                f2bf(bf2f(hb) + bf2f(xb_epi[rr * XBW + layer * HD + col]));
        } else if (outB) {
          outB[rr * ldo + col] = f2bf(v);
        } else {
          outF[rr * ldo + col] = v;
        }
      }
    }
  }
}

// ---------------------------------------------------------------------------
// Fused Horner: all K+1 steps for one (graph, 4-channel slab) in one block.
// fused && zstate[1]: GEMM epilogue already did the work -> immediate exit.
// General path: acc ping-pong in LDS, dis/cnt staged, zstate skipping.
// ---------------------------------------------------------------------------
__global__ __launch_bounds__(256, 1) void horner_kernel(
    const unsigned short* __restrict__ h,        // [NROWS][HD] bf16 pre-act
    const int* __restrict__ cnt, const float* __restrict__ dis,
    const unsigned short* __restrict__ colidx,
    const float* __restrict__ qf, const int* __restrict__ zstate,
    unsigned short* __restrict__ XB, unsigned short* __restrict__ bern,
    int layer, int fused) {
  __shared__ float accA[NB * 4];
  __shared__ float accB[NB * 4];
  __shared__ float dls[NB];
  __shared__ int   cls[NB];
  const int blk = blockIdx.x;                    // 512 = 8 graphs * 64 slabs
  const int b   = blk >> 6;
  const int ch0 = (blk & 63) * 4;
  const int t   = threadIdx.x;
  const size_t rowbase = (size_t)b * NB;

  if (zstate[1]) {
    if (fused) return;                           // epilogue already did it
    const float q0 = qf[0];
    for (int r = t; r < NB; r += 256) {
      union { unsigned short s[4]; uint2 u; } iv, ov, xv, bv;
      iv.u = *(const uint2*)&h[(rowbase + r) * HD + ch0];
#pragma unroll
      for (int j = 0; j < 4; ++j)
        ov.s[j] = f2bf(fmaxf(q0 * bf2f(iv.s[j]), 0.f));
      *(uint2*)&XB[(rowbase + r) * XBW + 768 + layer * HD + ch0] = ov.u;
      if (bern) {
        xv.u = *(const uint2*)&XB[(rowbase + r) * XBW + layer * HD + ch0];
#pragma unroll
        for (int j = 0; j < 4; ++j)
          bv.s[j] = f2bf(bf2f(ov.s[j]) + bf2f(xv.s[j]));
        *(uint2*)&bern[(rowbase + r) * 768 + layer * HD + ch0] = bv.u;
      }
    }
    return;
  }

  for (int r = t; r < NB; r += 256) {
    dls[r] = dis[rowbase + r];
    cls[r] = cnt[rowbase + r];
  }
  __syncthreads();
  float* cur = accA;
  float* nxt = accB;
  const int ch = t & 3;
  for (int m = KORD; m >= 0; --m) {
    if (m == 0 || !zstate[m]) {
      const float qm = qf[m];
      const int gather = !zstate[m + 1];
      for (int r = t >> 2; r < NB; r += 64) {
        float s = 0.f;
        if (gather) {
          const int deg = cls[r];
          const float di = dls[r];
          const unsigned short* ci = colidx + (rowbase + r) * MAXDEG;
          for (int e = 0; e < deg; ++e) {
            const int nb = ci[e];
            s += di * dls[nb] * cur[nb * 4 + ch];
          }
        }
        if (qm != 0.f) s += qm * bf2f(h[(rowbase + r) * HD + ch0 + ch]);
        if (m == 0) {
          const float hv = fmaxf(s, 0.f);
          XB[(rowbase + r) * XBW + 768 + layer * HD + ch0 + ch] = f2bf(hv);
          if (bern)
            bern[(rowbase + r) * 768 + layer * HD + ch0 + ch] = f2bf(
                hv + bf2f(XB[(rowbase + r) * XBW + layer * HD + ch0 + ch]));
        } else {
          nxt[r * 4 + ch] = s;
        }
      }
    }
    __syncthreads();
    float* tp = cur; cur = nxt; nxt = tp;
  }
}

// ---------------------------------------------------------------------------
extern "C" void kernel_launch(void* const* d_in, const int* in_sizes, int n_in,
                              void* d_out, int out_size, void* d_ws, size_t ws_size,
                              hipStream_t stream) {
  const float* adj  = (const float*)d_in[0];
  const float* x    = (const float*)d_in[1];
  const float* coe  = (const float*)d_in[2];
  const float* W0   = (const float*)d_in[3];
  const float* b0   = (const float*)d_in[4];
  const float* W1   = (const float*)d_in[5];
  const float* b1   = (const float*)d_in[6];
  const float* W2   = (const float*)d_in[7];
  const float* b2   = (const float*)d_in[8];
  const float* Wout = (const float*)d_in[9];
  const float* bout = (const float*)d_in[10];
  float* outp = (float*)d_out;

  // d_out scratch (dead before final GEMM): bufH [16384][256] bf16 @ 0 (8MB),
  // PX [16384][512] bf16 @ +8MB (16MB) = x-partials P1x|P2x.
  unsigned short* bufH = (unsigned short*)outp;
  unsigned short* PX   = bufH + (size_t)NROWS * HD;

  char* ws = (char*)d_ws;
  size_t off = 0;
  float* qf     = (float*)(ws + off); off += 256;
  int*   zstate = (int*)(ws + off);   off += 256;
  float* biasX  = (float*)(ws + off); off += 768 * 4;
  int*   cnt    = (int*)(ws + off);   off += 65536;
  float* dis    = (float*)(ws + off); off += 65536;
  unsigned short* colidx = (unsigned short*)(ws + off); off += (size_t)NROWS * MAXDEG * 2;
  unsigned short* XB     = (unsigned short*)(ws + off); off += (size_t)NROWS * XBW * 2;
  unsigned short* WtX  = (unsigned short*)(ws + off); off += (size_t)768 * 768 * 2;
  unsigned short* WtB1 = (unsigned short*)(ws + off); off += (size_t)256 * 256 * 2;
  unsigned short* WtB2 = (unsigned short*)(ws + off); off += (size_t)256 * 512 * 2;
  unsigned short* WtO  = (unsigned short*)(ws + off); off += (size_t)768 * 1536 * 2;
  unsigned short* bern = (unsigned short*)(ws + off);
  const size_t need = off + (size_t)NROWS * 768 * 2;
  const int split = ws_size >= need;                   // bern fits in ws?
  unsigned short* bernp = split ? bern : (unsigned short*)nullptr;

  hipLaunchKernelGGL(qz_kernel, dim3(1), dim3(128), 0, stream,
                     coe, b0, qf, zstate, biasX);
  hipLaunchKernelGGL(prep_kernel, dim3(8064), dim3(256), 0, stream,
                     adj, x, W0, W1, W2, Wout, zstate,
                     cnt, dis, colidx, XB, WtX, WtB1, WtB2, WtO);

  const int PXL = 1 << 30;   // "no px split"

  // GEMM1 (wide x-GEMM): [P0|P1x|P2x] = x @ [W0|W1a|W2a] + [b0|0|0]
  //   cols<256: layer-0 output (fast-Horner fused / bufH); cols>=256 -> PX.
  hipLaunchKernelGGL(mfma_gemm_kernel, dim3(6, 128), dim3(256), 0, stream,
                     768, XB, XBW, WtX, 768, biasX,
                     (const unsigned short*)nullptr, 0,
                     PX, 512, 256,
                     (float*)nullptr, bufH, HD,
                     qf, zstate, XB, bernp, 0);
  hipLaunchKernelGGL(horner_kernel, dim3(512), dim3(256), 0, stream,
                     bufH, cnt, dis, colidx, qf, zstate, XB, bernp, 0, 1);

  // GEMM2: P1 = P1x + h0 @ W1b + b1   (K=256)
  hipLaunchKernelGGL(mfma_gemm_kernel, dim3(2, 128), dim3(256), 0, stream,
                     256, XB + 768, XBW, WtB1, 256, b1,
                     PX, 512,
                     (unsigned short*)nullptr, 0, PXL,
                     (float*)nullptr, bufH, HD,
                     qf, zstate, XB, bernp, 1);
  hipLaunchKernelGGL(horner_kernel, dim3(512), dim3(256), 0, stream,
                     bufH, cnt, dis, colidx, qf, zstate, XB, bernp, 1, 1);

  // GEMM3: P2 = P2x + [h0,h1] @ W2bc + b2   (K=512)
  hipLaunchKernelGGL(mfma_gemm_kernel, dim3(2, 128), dim3(256), 0, stream,
                     512, XB + 768, XBW, WtB2, 512, b2,
                     PX + 256, 512,
                     (unsigned short*)nullptr, 0, PXL,
                     (float*)nullptr, bufH, HD,
                     qf, zstate, XB, bernp, 2);
  hipLaunchKernelGGL(horner_kernel, dim3(512), dim3(256), 0, stream,
                     bufH, cnt, dis, colidx, qf, zstate, XB, bernp, 2, 1);

  // Final: out = bern @ Wout + bout (split) or [x|h]@[Wout;Wout] (fallback)
  if (split)
    hipLaunchKernelGGL(mfma_gemm_kernel, dim3(6, 128), dim3(256), 0, stream,
                       768, bern, 768, WtO, 1536, bout,
                       (const unsigned short*)nullptr, 0,
                       (unsigned short*)nullptr, 0, PXL,
                       outp, (unsigned short*)nullptr, 768,
                       qf, zstate, (unsigned short*)nullptr,
                       (unsigned short*)nullptr, 0);
  else
    hipLaunchKernelGGL(mfma_gemm_kernel, dim3(6, 128), dim3(256), 0, stream,
                       1536, XB, XBW, WtO, 1536, bout,
                       (const unsigned short*)nullptr, 0,
                       (unsigned short*)nullptr, 0, PXL,
                       outp, (unsigned short*)nullptr, 768,
                       qf, zstate, (unsigned short*)nullptr,
                       (unsigned short*)nullptr, 0);
}

// Round 8
// 153.906 us; speedup vs baseline: 1.4816x; 1.4816x over previous
//
#include <hip/hip_runtime.h>

#define KORD   10
#define MAXDEG 64
#define NB     2048        // nodes per graph
#define NROWS  16384       // 8 * 2048
#define HD     256         // hidden per conv
#define XBW    1536        // XB width: [x(768) | h0(256) | h1(256) | h2(256)]

typedef __attribute__((ext_vector_type(8))) short short8;
typedef __attribute__((ext_vector_type(4))) float f32x4;

__device__ inline unsigned short f2bf(float f) {
  union { float f; unsigned u; } v; v.f = f;
  unsigned r = v.u + 0x7fff + ((v.u >> 16) & 1);   // round-to-nearest-even
  return (unsigned short)(r >> 16);
}
__device__ inline float bf2f(unsigned short b) {
  union { unsigned u; float f; } v; v.u = ((unsigned)b) << 16;
  return v.f;
}

#define AS1 __attribute__((address_space(1)))
#define AS3 __attribute__((address_space(3)))
__device__ inline void gload16(const void* g, void* l) {
  __builtin_amdgcn_global_load_lds((const AS1 void*)g, (AS3 void*)l, 16, 0, 0);
}

// ---------------------------------------------------------------------------
__device__ inline double binom_d(int n, int r) {
  if (r < 0 || r > n) return 0.0;
  double v = 1.0;
  for (int i = 1; i <= r; ++i) v = v * (double)(n - r + i) / (double)i;
  return v;
}

// ---------------------------------------------------------------------------
// q[m] = [z^m] sum_k relu(coe[k]) * C(K,k)/2^K * (1-z)^k (1+z)^{K-k}
// zstate[m] = 1 iff q[j]==0 for all j>=m. Exact in fp64 for dyadic coe.
// ---------------------------------------------------------------------------
__global__ __launch_bounds__(128) void qz_kernel(const float* __restrict__ coe,
                                                 float* __restrict__ qf,
                                                 int* __restrict__ zstate) {
  __shared__ double part[(KORD + 1) * (KORD + 1)];   // [k][m]
  __shared__ double qs[KORD + 1];
  const int t = threadIdx.x;
  if (t < (KORD + 1) * (KORD + 1)) {
    const int k = t / (KORD + 1), m = t % (KORD + 1);
    double tt = (double)coe[k];
    if (tt < 0.0) tt = 0.0;                          // relu(coe)
    const double ck = tt * binom_d(KORD, k) / 1024.0;
    double s = 0.0;
    for (int j = 0; j <= k && j <= m; ++j) {
      const int rem = m - j;
      if (rem <= KORD - k) {
        const double term = binom_d(k, j) * binom_d(KORD - k, rem);
        s += (j & 1) ? -term : term;
      }
    }
    part[t] = ck * s;
  }
  __syncthreads();
  if (t <= KORD) {
    double q = 0.0;
    for (int k = 0; k <= KORD; ++k) q += part[k * (KORD + 1) + t];
    qs[t] = q;
    qf[t] = (float)q;
  }
  __syncthreads();
  if (t == 0) {
    zstate[KORD + 1] = 1;
    int z = 1;
    for (int m = KORD; m >= 0; --m) {
      if (qs[m] != 0.0) z = 0;
      zstate[m] = z;
    }
  }
}

// ---------------------------------------------------------------------------
// Fused prep: one dispatch, branch by block range.
//   [0,4096)      build_adj (runtime-dead when zstate[1] -> early exit)
//   [4096,6144)   xcvt: x fp32 -> XB bf16 cols [0,768)
//   [6144,8064)   wcvt x5: W [K][N] fp32 -> Wt [N][ldt] bf16 transposed
// ---------------------------------------------------------------------------
__global__ __launch_bounds__(256) void prep_kernel(
    const float* __restrict__ adj, const float* __restrict__ x,
    const float* __restrict__ W0, const float* __restrict__ W1,
    const float* __restrict__ W2, const float* __restrict__ Wout,
    const int* __restrict__ zstate,
    int* __restrict__ cnt, float* __restrict__ dis,
    unsigned short* __restrict__ colidx,
    unsigned short* __restrict__ XB,
    unsigned short* __restrict__ Wt0, unsigned short* __restrict__ Wt1,
    unsigned short* __restrict__ Wt2, unsigned short* __restrict__ WtO) {
  __shared__ float tile[32][33];
  const int blk = blockIdx.x;
  const int t = threadIdx.x;

  if (blk < 4096) {                       // ---- build_adj ----
    if (zstate[1]) return;                // outputs never consumed: skip
    const int wave = t >> 6;
    const int lane = t & 63;
    const int row  = blk * 4 + wave;
    const float4* arow4 = (const float4*)(adj + (size_t)row * NB);
    unsigned short* ci = colidx + (size_t)row * MAXDEG;
    float4 v[8];
#pragma unroll
    for (int i = 0; i < 8; ++i) v[i] = arow4[i * 64 + lane];
    const unsigned long long lower = (1ull << lane) - 1ull;
    int base = 0;
#pragma unroll
    for (int i = 0; i < 8; ++i) {
      const int col = i * 256 + lane * 4;
      const int b0 = v[i].x > 0.f, b1 = v[i].y > 0.f;
      const int b2 = v[i].z > 0.f, b3 = v[i].w > 0.f;
      const unsigned long long m0 = __ballot(b0), m1 = __ballot(b1);
      const unsigned long long m2 = __ballot(b2), m3 = __ballot(b3);
      int pre = base + __popcll(m0 & lower) + __popcll(m1 & lower) +
                __popcll(m2 & lower) + __popcll(m3 & lower);
      if (b0) { if (pre < MAXDEG) ci[pre] = (unsigned short)col; ++pre; }
      if (b1) { if (pre < MAXDEG) ci[pre] = (unsigned short)(col + 1); ++pre; }
      if (b2) { if (pre < MAXDEG) ci[pre] = (unsigned short)(col + 2); ++pre; }
      if (b3) { if (pre < MAXDEG) ci[pre] = (unsigned short)(col + 3); ++pre; }
      base += __popcll(m0) + __popcll(m1) + __popcll(m2) + __popcll(m3);
    }
    if (lane == 0) {
      cnt[row] = base > MAXDEG ? MAXDEG : base;
      dis[row] = base > 0 ? rsqrtf((float)base) : 0.0f;
    }
    return;
  }

  if (blk < 6144) {                       // ---- xcvt: 8 rows per block ----
    const int r0 = (blk - 4096) * 8;
    for (int i = t; i < 8 * 192; i += 256) {
      const int r = r0 + (i / 192);
      const int c = (i % 192) * 4;
      float4 v = *(const float4*)&x[(size_t)r * 768 + c];
      union { unsigned short s[4]; uint2 u; } o;
      o.s[0] = f2bf(v.x); o.s[1] = f2bf(v.y);
      o.s[2] = f2bf(v.z); o.s[3] = f2bf(v.w);
      *(uint2*)&XB[(size_t)r * XBW + c] = o.u;
    }
    return;
  }

  // ---- wcvt (5 jobs) ----
  const float* W; unsigned short* Wt; int N, ldt, koff, gx, lb;
  int b = blk - 6144;
  if (b < 192)       { W = W0;   Wt = Wt0; N = 256; ldt = 768;  koff = 0;   gx = 24; lb = b; }
  else if (b < 448)  { W = W1;   Wt = Wt1; N = 256; ldt = 1024; koff = 0;   gx = 32; lb = b - 192; }
  else if (b < 768)  { W = W2;   Wt = Wt2; N = 256; ldt = 1280; koff = 0;   gx = 40; lb = b - 448; }
  else if (b < 1344) { W = Wout; Wt = WtO; N = 768; ldt = 1536; koff = 0;   gx = 24; lb = b - 768; }
  else               { W = Wout; Wt = WtO; N = 768; ldt = 1536; koff = 768; gx = 24; lb = b - 1344; }
  const int k0 = (lb % gx) * 32, n0 = (lb / gx) * 32;
  const int tx = t & 31, ty = t >> 5;
#pragma unroll
  for (int i = 0; i < 4; ++i)
    tile[ty + 8 * i][tx] = W[(size_t)(k0 + ty + 8 * i) * N + n0 + tx];
  __syncthreads();
#pragma unroll
  for (int i = 0; i < 4; ++i)
    Wt[(size_t)(n0 + ty + 8 * i) * ldt + koff + k0 + tx] =
        f2bf(tile[tx][ty + 8 * i]);
}

// ---------------------------------------------------------------------------
// bf16 MFMA GEMM, BM templated: out[M, N] = A[M,Kd] @ Wt[N,Kd]^T + bias
// BMT x 128 tile, BK=32, 4 waves (2x2), 4-buffer LDS ring, counted vmcnt
// (never 0 in steady state), raw s_barrier: ONE barrier per K-step.
// BMT=128: 16 stage-chunks (4/wave), vmcnt 8/4/0. Grid 3 blocks/CU @ N=768.
// BMT=64:  12 stage-chunks (3/wave), vmcnt 6/3/0. Grid 2 blocks/CU @ N=256
//          (the round-8 change: layer GEMMs were 1 block/CU, latency-bound).
// 16B-slot XOR swizzle; bijective XCD chunk swizzle.
// Epilogue: zstate[1]&&xb_epi -> fused fast-Horner relu(q0*v) -> XB (+bern);
// else outB (bf16) / outF (fp32).
// ---------------------------------------------------------------------------
template <int BMT>
__global__ __launch_bounds__(256) void mfma_gemm_kernel(
    int Kd,
    const unsigned short* __restrict__ A, int lda,
    const unsigned short* __restrict__ Wt, int ldw,
    const float* __restrict__ bias,
    float* __restrict__ outF, unsigned short* __restrict__ outB, int ldo,
    const float* __restrict__ qf, const int* __restrict__ zstate,
    unsigned short* __restrict__ xb_epi, unsigned short* __restrict__ bern_epi,
    int layer) {
  constexpr int MF  = BMT / 32;        // m-fragments per wave (2 or 4)
  constexpr int ACH = BMT / 16;        // A stage-chunks (4 or 8)
  constexpr int CPW = (ACH + 8) / 4;   // chunks per wave (3 or 4)
  __shared__ __align__(16) unsigned short Asl[4][BMT * 32];
  __shared__ __align__(16) unsigned short Bsl[4][128 * 32];
  const int t    = threadIdx.x;
  const int lane = t & 63;
  const int wid  = t >> 6;
  const int wr   = wid >> 1, wc = wid & 1;

  const int gx  = gridDim.x;
  const int nwg = gx * gridDim.y;
  int bid = blockIdx.y * gx + blockIdx.x;
  if ((nwg & 7) == 0) bid = (bid & 7) * (nwg >> 3) + (bid >> 3);
  const int row0 = (bid / gx) * BMT;
  const int col0 = (bid % gx) * 128;

  f32x4 acc[MF][4] = {};

  const int swz    = ((lane & 3) ^ ((lane >> 3) & 3)) * 8;
  const int subrow = lane >> 2;
  const int fr = lane & 15;
  const int fq = lane >> 4;

  const int nkt = Kd >> 5;

  auto stage = [&](int kt, int pb) {
    const int kbase = kt << 5;
#pragma unroll
    for (int i = 0; i < CPW; ++i) {
      const int c = wid * CPW + i;               // 0..CPW*4-1; <ACH = A, else B
      if (c < ACH) {
        const int r = row0 + c * 16 + subrow;
        gload16(A + (size_t)r * lda + kbase + swz, &Asl[pb][c * 512]);
      } else {
        const int cc = c - ACH;
        const int r = col0 + cc * 16 + subrow;
        gload16(Wt + (size_t)r * ldw + kbase + swz, &Bsl[pb][cc * 512]);
      }
    }
  };

  stage(0, 0);
  if (nkt > 1) stage(1, 1);

  for (int kt = 0; kt < nkt; ++kt) {
    const int pb = kt & 3;
    if (kt + 2 < nkt) {
      stage(kt + 2, (kt + 2) & 3);
      if constexpr (BMT == 128)
        asm volatile("s_waitcnt vmcnt(8)" ::: "memory");
      else
        asm volatile("s_waitcnt vmcnt(6)" ::: "memory");
    } else if (kt + 1 < nkt) {
      if constexpr (BMT == 128)
        asm volatile("s_waitcnt vmcnt(4)" ::: "memory");
      else
        asm volatile("s_waitcnt vmcnt(3)" ::: "memory");
    } else {
      asm volatile("s_waitcnt vmcnt(0)" ::: "memory");
    }
    __builtin_amdgcn_s_barrier();
    asm volatile("" ::: "memory");

    short8 af[MF], bfr[4];
#pragma unroll
    for (int m = 0; m < MF; ++m) {
      const int r = wr * (MF * 16) + m * 16 + fr;
      const int colb = (fq * 16) ^ (((r >> 1) & 3) << 4);
      af[m] = *(const short8*)((const char*)&Asl[pb][0] + r * 64 + colb);
    }
#pragma unroll
    for (int n = 0; n < 4; ++n) {
      const int r = wc * 64 + n * 16 + fr;
      const int colb = (fq * 16) ^ (((r >> 1) & 3) << 4);
      bfr[n] = *(const short8*)((const char*)&Bsl[pb][0] + r * 64 + colb);
    }
    __builtin_amdgcn_s_setprio(1);
#pragma unroll
    for (int m = 0; m < MF; ++m)
#pragma unroll
      for (int n = 0; n < 4; ++n)
        acc[m][n] = __builtin_amdgcn_mfma_f32_16x16x32_bf16(af[m], bfr[n],
                                                            acc[m][n], 0, 0, 0);
    __builtin_amdgcn_s_setprio(0);
  }

  // epilogue: C/D layout col = lane&15, row = (lane>>4)*4 + reg
  int fastepi = 0; float q0 = 0.f;
  if (xb_epi) { fastepi = zstate[1]; q0 = qf[0]; }
#pragma unroll
  for (int n = 0; n < 4; ++n) {
    const int col = col0 + wc * 64 + n * 16 + fr;
    const float bv = bias[col];
#pragma unroll
    for (int m = 0; m < MF; ++m) {
      const int rbase = row0 + wr * (MF * 16) + m * 16 + fq * 4;
#pragma unroll
      for (int r = 0; r < 4; ++r) {
        const float v = acc[m][n][r] + bv;
        const size_t rr = (size_t)(rbase + r);
        if (fastepi) {
          const float hv = fmaxf(q0 * v, 0.f);
          const unsigned short hb = f2bf(hv);
          xb_epi[rr * XBW + 768 + layer * HD + col] = hb;
          if (bern_epi)
            bern_epi[rr * 768 + layer * HD + col] =
                f2bf(bf2f(hb) + bf2f(xb_epi[rr * XBW + layer * HD + col]));
        } else if (outB) {
          outB[rr * ldo + col] = f2bf(v);
        } else {
          outF[rr * ldo + col] = v;
        }
      }
    }
  }
}

// ---------------------------------------------------------------------------
// Fused Horner: all K+1 steps for one (graph, 4-channel slab) in one block.
// fused && zstate[1]: GEMM epilogue already did the work -> immediate exit.
// General path: acc ping-pong in LDS, dis/cnt staged, zstate skipping.
// ---------------------------------------------------------------------------
__global__ __launch_bounds__(256, 1) void horner_kernel(
    const unsigned short* __restrict__ h,        // [NROWS][HD] bf16 pre-act
    const int* __restrict__ cnt, const float* __restrict__ dis,
    const unsigned short* __restrict__ colidx,
    const float* __restrict__ qf, const int* __restrict__ zstate,
    unsigned short* __restrict__ XB, unsigned short* __restrict__ bern,
    int layer, int fused) {
  __shared__ float accA[NB * 4];
  __shared__ float accB[NB * 4];
  __shared__ float dls[NB];
  __shared__ int   cls[NB];
  const int blk = blockIdx.x;                    // 512 = 8 graphs * 64 slabs
  const int b   = blk >> 6;
  const int ch0 = (blk & 63) * 4;
  const int t   = threadIdx.x;
  const size_t rowbase = (size_t)b * NB;

  if (zstate[1]) {
    if (fused) return;                           // epilogue already did it
    const float q0 = qf[0];
    for (int r = t; r < NB; r += 256) {
      union { unsigned short s[4]; uint2 u; } iv, ov, xv, bv;
      iv.u = *(const uint2*)&h[(rowbase + r) * HD + ch0];
#pragma unroll
      for (int j = 0; j < 4; ++j)
        ov.s[j] = f2bf(fmaxf(q0 * bf2f(iv.s[j]), 0.f));
      *(uint2*)&XB[(rowbase + r) * XBW + 768 + layer * HD + ch0] = ov.u;
      if (bern) {
        xv.u = *(const uint2*)&XB[(rowbase + r) * XBW + layer * HD + ch0];
#pragma unroll
        for (int j = 0; j < 4; ++j)
          bv.s[j] = f2bf(bf2f(ov.s[j]) + bf2f(xv.s[j]));
        *(uint2*)&bern[(rowbase + r) * 768 + layer * HD + ch0] = bv.u;
      }
    }
    return;
  }

  for (int r = t; r < NB; r += 256) {
    dls[r] = dis[rowbase + r];
    cls[r] = cnt[rowbase + r];
  }
  __syncthreads();
  float* cur = accA;
  float* nxt = accB;
  const int ch = t & 3;
  for (int m = KORD; m >= 0; --m) {
    if (m == 0 || !zstate[m]) {
      const float qm = qf[m];
      const int gather = !zstate[m + 1];
      for (int r = t >> 2; r < NB; r += 64) {
        float s = 0.f;
        if (gather) {
          const int deg = cls[r];
          const float di = dls[r];
          const unsigned short* ci = colidx + (rowbase + r) * MAXDEG;
          for (int e = 0; e < deg; ++e) {
            const int nb = ci[e];
            s += di * dls[nb] * cur[nb * 4 + ch];
          }
        }
        if (qm != 0.f) s += qm * bf2f(h[(rowbase + r) * HD + ch0 + ch]);
        if (m == 0) {
          const float hv = fmaxf(s, 0.f);
          XB[(rowbase + r) * XBW + 768 + layer * HD + ch0 + ch] = f2bf(hv);
          if (bern)
            bern[(rowbase + r) * 768 + layer * HD + ch0 + ch] = f2bf(
                hv + bf2f(XB[(rowbase + r) * XBW + layer * HD + ch0 + ch]));
        } else {
          nxt[r * 4 + ch] = s;
        }
      }
    }
    __syncthreads();
    float* tp = cur; cur = nxt; nxt = tp;
  }
}

// ---------------------------------------------------------------------------
extern "C" void kernel_launch(void* const* d_in, const int* in_sizes, int n_in,
                              void* d_out, int out_size, void* d_ws, size_t ws_size,
                              hipStream_t stream) {
  const float* adj  = (const float*)d_in[0];
  const float* x    = (const float*)d_in[1];
  const float* coe  = (const float*)d_in[2];
  const float* W0   = (const float*)d_in[3];
  const float* b0   = (const float*)d_in[4];
  const float* W1   = (const float*)d_in[5];
  const float* b1   = (const float*)d_in[6];
  const float* W2   = (const float*)d_in[7];
  const float* b2   = (const float*)d_in[8];
  const float* Wout = (const float*)d_in[9];
  const float* bout = (const float*)d_in[10];
  float* outp = (float*)d_out;

  // bufH (GEMM output when the general Horner path is live, bf16) lives in
  // d_out; dead by the time the final GEMM overwrites d_out.
  unsigned short* bufH = (unsigned short*)outp;

  char* ws = (char*)d_ws;
  size_t off = 0;
  float* qf     = (float*)(ws + off); off += 256;
  int*   zstate = (int*)(ws + off);   off += 256;
  int*   cnt    = (int*)(ws + off);   off += 65536;
  float* dis    = (float*)(ws + off); off += 65536;
  unsigned short* colidx = (unsigned short*)(ws + off); off += (size_t)NROWS * MAXDEG * 2;
  unsigned short* XB     = (unsigned short*)(ws + off); off += (size_t)NROWS * XBW * 2;
  unsigned short* Wt0 = (unsigned short*)(ws + off); off += (size_t)256 * 768 * 2;
  unsigned short* Wt1 = (unsigned short*)(ws + off); off += (size_t)256 * 1024 * 2;
  unsigned short* Wt2 = (unsigned short*)(ws + off); off += (size_t)256 * 1280 * 2;
  unsigned short* WtO = (unsigned short*)(ws + off); off += (size_t)768 * 1536 * 2;
  unsigned short* bern = (unsigned short*)(ws + off);
  const size_t need = off + (size_t)NROWS * 768 * 2;   // ~77.9 MB
  const int split = ws_size >= need;                   // bern fits in ws?
  unsigned short* bernp = split ? bern : (unsigned short*)nullptr;

  hipLaunchKernelGGL(qz_kernel, dim3(1), dim3(128), 0, stream, coe, qf, zstate);
  hipLaunchKernelGGL(prep_kernel, dim3(8064), dim3(256), 0, stream,
                     adj, x, W0, W1, W2, Wout, zstate,
                     cnt, dis, colidx, XB, Wt0, Wt1, Wt2, WtO);

  // layer l: h = [x|h0|..] @ Wl + bl (bf16 MFMA BM=64 tiles, 512 blocks,
  // fast-Horner fused in epilogue when zstate[1]); Horner early-exits then.
  auto layer = [&](int Kd, const unsigned short* Wt, const float* bias, int l) {
    hipLaunchKernelGGL(mfma_gemm_kernel<64>, dim3(2, 256), dim3(256), 0, stream,
                       Kd, XB, XBW, Wt, Kd, bias, (float*)nullptr, bufH, HD,
                       qf, zstate, XB, bernp, l);
    hipLaunchKernelGGL(horner_kernel, dim3(512), dim3(256), 0, stream,
                       bufH, cnt, dis, colidx, qf, zstate, XB, bernp, l, 1);
  };
  layer(768,  Wt0, b0, 0);
  layer(1024, Wt1, b1, 1);
  layer(1280, Wt2, b2, 2);

  // out = bern @ Wout + bout (split: K=768 on materialized bern)
  //     = [x | h0h1h2] @ [Wout ; Wout] + bout (fallback: K=1536 dup)
  if (split)
    hipLaunchKernelGGL(mfma_gemm_kernel<128>, dim3(6, 128), dim3(256), 0, stream,
                       768, bern, 768, WtO, 1536, bout,
                       outp, (unsigned short*)nullptr, 768,
                       qf, zstate, (unsigned short*)nullptr,
                       (unsigned short*)nullptr, 0);
  else
    hipLaunchKernelGGL(mfma_gemm_kernel<128>, dim3(6, 128), dim3(256), 0, stream,
                       1536, XB, XBW, WtO, 1536, bout,
                       outp, (unsigned short*)nullptr, 768,
                       qf, zstate, (unsigned short*)nullptr,
                       (unsigned short*)nullptr, 0);
}

// Round 9
// 150.905 us; speedup vs baseline: 1.5111x; 1.0199x over previous
//
#include <hip/hip_runtime.h>

#define KORD   10
#define MAXDEG 64
#define NB     2048        // nodes per graph
#define NROWS  16384       // 8 * 2048
#define HD     256         // hidden per conv
#define XBW    1536        // XB width: [x(768) | h0(256) | h1(256) | h2(256)]

typedef __attribute__((ext_vector_type(8))) short short8;
typedef __attribute__((ext_vector_type(4))) float f32x4;

__device__ inline unsigned short f2bf(float f) {
  union { float f; unsigned u; } v; v.f = f;
  unsigned r = v.u + 0x7fff + ((v.u >> 16) & 1);   // round-to-nearest-even
  return (unsigned short)(r >> 16);
}
__device__ inline float bf2f(unsigned short b) {
  union { unsigned u; float f; } v; v.u = ((unsigned)b) << 16;
  return v.f;
}

#define AS1 __attribute__((address_space(1)))
#define AS3 __attribute__((address_space(3)))
__device__ inline void gload16(const void* g, void* l) {
  __builtin_amdgcn_global_load_lds((const AS1 void*)g, (AS3 void*)l, 16, 0, 0);
}

// ---------------------------------------------------------------------------
__device__ inline double binom_d(int n, int r) {
  if (r < 0 || r > n) return 0.0;
  double v = 1.0;
  for (int i = 1; i <= r; ++i) v = v * (double)(n - r + i) / (double)i;
  return v;
}

// ---------------------------------------------------------------------------
// q[m] = [z^m] sum_k relu(coe[k]) * C(K,k)/2^K * (1-z)^k (1+z)^{K-k}
// zstate[m] = 1 iff q[j]==0 for all j>=m. Exact in fp64 for dyadic coe.
// ---------------------------------------------------------------------------
__global__ __launch_bounds__(128) void qz_kernel(const float* __restrict__ coe,
                                                 float* __restrict__ qf,
                                                 int* __restrict__ zstate) {
  __shared__ double part[(KORD + 1) * (KORD + 1)];   // [k][m]
  __shared__ double qs[KORD + 1];
  const int t = threadIdx.x;
  if (t < (KORD + 1) * (KORD + 1)) {
    const int k = t / (KORD + 1), m = t % (KORD + 1);
    double tt = (double)coe[k];
    if (tt < 0.0) tt = 0.0;                          // relu(coe)
    const double ck = tt * binom_d(KORD, k) / 1024.0;
    double s = 0.0;
    for (int j = 0; j <= k && j <= m; ++j) {
      const int rem = m - j;
      if (rem <= KORD - k) {
        const double term = binom_d(k, j) * binom_d(KORD - k, rem);
        s += (j & 1) ? -term : term;
      }
    }
    part[t] = ck * s;
  }
  __syncthreads();
  if (t <= KORD) {
    double q = 0.0;
    for (int k = 0; k <= KORD; ++k) q += part[k * (KORD + 1) + t];
    qs[t] = q;
    qf[t] = (float)q;
  }
  __syncthreads();
  if (t == 0) {
    zstate[KORD + 1] = 1;
    int z = 1;
    for (int m = KORD; m >= 0; --m) {
      if (qs[m] != 0.0) z = 0;
      zstate[m] = z;
    }
  }
}

// ---------------------------------------------------------------------------
// Fused prep: one dispatch, branch by block range.
//   [0,4096)      build_adj (runtime-dead when zstate[1] -> early exit)
//   [4096,6144)   xcvt: x fp32 -> XB bf16 cols [0,768)
//   [6144,8064)   wcvt x5: W [K][N] fp32 -> Wt [N][ldt] bf16 transposed
// ---------------------------------------------------------------------------
__global__ __launch_bounds__(256) void prep_kernel(
    const float* __restrict__ adj, const float* __restrict__ x,
    const float* __restrict__ W0, const float* __restrict__ W1,
    const float* __restrict__ W2, const float* __restrict__ Wout,
    const int* __restrict__ zstate,
    int* __restrict__ cnt, float* __restrict__ dis,
    unsigned short* __restrict__ colidx,
    unsigned short* __restrict__ XB,
    unsigned short* __restrict__ Wt0, unsigned short* __restrict__ Wt1,
    unsigned short* __restrict__ Wt2, unsigned short* __restrict__ WtO) {
  __shared__ float tile[32][33];
  const int blk = blockIdx.x;
  const int t = threadIdx.x;

  if (blk < 4096) {                       // ---- build_adj ----
    if (zstate[1]) return;                // outputs never consumed: skip
    const int wave = t >> 6;
    const int lane = t & 63;
    const int row  = blk * 4 + wave;
    const float4* arow4 = (const float4*)(adj + (size_t)row * NB);
    unsigned short* ci = colidx + (size_t)row * MAXDEG;
    float4 v[8];
#pragma unroll
    for (int i = 0; i < 8; ++i) v[i] = arow4[i * 64 + lane];
    const unsigned long long lower = (1ull << lane) - 1ull;
    int base = 0;
#pragma unroll
    for (int i = 0; i < 8; ++i) {
      const int col = i * 256 + lane * 4;
      const int b0 = v[i].x > 0.f, b1 = v[i].y > 0.f;
      const int b2 = v[i].z > 0.f, b3 = v[i].w > 0.f;
      const unsigned long long m0 = __ballot(b0), m1 = __ballot(b1);
      const unsigned long long m2 = __ballot(b2), m3 = __ballot(b3);
      int pre = base + __popcll(m0 & lower) + __popcll(m1 & lower) +
                __popcll(m2 & lower) + __popcll(m3 & lower);
      if (b0) { if (pre < MAXDEG) ci[pre] = (unsigned short)col; ++pre; }
      if (b1) { if (pre < MAXDEG) ci[pre] = (unsigned short)(col + 1); ++pre; }
      if (b2) { if (pre < MAXDEG) ci[pre] = (unsigned short)(col + 2); ++pre; }
      if (b3) { if (pre < MAXDEG) ci[pre] = (unsigned short)(col + 3); ++pre; }
      base += __popcll(m0) + __popcll(m1) + __popcll(m2) + __popcll(m3);
    }
    if (lane == 0) {
      cnt[row] = base > MAXDEG ? MAXDEG : base;
      dis[row] = base > 0 ? rsqrtf((float)base) : 0.0f;
    }
    return;
  }

  if (blk < 6144) {                       // ---- xcvt: 8 rows per block ----
    const int r0 = (blk - 4096) * 8;
    for (int i = t; i < 8 * 192; i += 256) {
      const int r = r0 + (i / 192);
      const int c = (i % 192) * 4;
      float4 v = *(const float4*)&x[(size_t)r * 768 + c];
      union { unsigned short s[4]; uint2 u; } o;
      o.s[0] = f2bf(v.x); o.s[1] = f2bf(v.y);
      o.s[2] = f2bf(v.z); o.s[3] = f2bf(v.w);
      *(uint2*)&XB[(size_t)r * XBW + c] = o.u;
    }
    return;
  }

  // ---- wcvt (5 jobs) ----
  const float* W; unsigned short* Wt; int N, ldt, koff, gx, lb;
  int b = blk - 6144;
  if (b < 192)       { W = W0;   Wt = Wt0; N = 256; ldt = 768;  koff = 0;   gx = 24; lb = b; }
  else if (b < 448)  { W = W1;   Wt = Wt1; N = 256; ldt = 1024; koff = 0;   gx = 32; lb = b - 192; }
  else if (b < 768)  { W = W2;   Wt = Wt2; N = 256; ldt = 1280; koff = 0;   gx = 40; lb = b - 448; }
  else if (b < 1344) { W = Wout; Wt = WtO; N = 768; ldt = 1536; koff = 0;   gx = 24; lb = b - 768; }
  else               { W = Wout; Wt = WtO; N = 768; ldt = 1536; koff = 768; gx = 24; lb = b - 1344; }
  const int k0 = (lb % gx) * 32, n0 = (lb / gx) * 32;
  const int tx = t & 31, ty = t >> 5;
#pragma unroll
  for (int i = 0; i < 4; ++i)
    tile[ty + 8 * i][tx] = W[(size_t)(k0 + ty + 8 * i) * N + n0 + tx];
  __syncthreads();
#pragma unroll
  for (int i = 0; i < 4; ++i)
    Wt[(size_t)(n0 + ty + 8 * i) * ldt + koff + k0 + tx] =
        f2bf(tile[tx][ty + 8 * i]);
}

// ---------------------------------------------------------------------------
// bf16 MFMA GEMM, tile templated: out[M, N] = A[M,Kd] @ Wt[N,Kd]^T + bias
// BMT x BNT tile, BK=32, 4 waves (2x2), 4-buffer LDS ring, counted vmcnt
// (never 0 in steady state; constants = 2*CPW / CPW / 0), raw s_barrier:
// ONE barrier per K-step, 2 stages always in flight.
//   64x64:  LDS 32KB, grid (4,256) -> 4 blocks/CU, 16 waves/CU (layer GEMMs)
//   64x128: LDS 48KB, grid (6,256) -> 3 blocks/CU (final GEMM)
// 16B-slot XOR swizzle; bijective XCD chunk swizzle.
// Epilogue: zstate[1]&&xb_epi -> fused fast-Horner relu(q0*v) -> XB (+bern);
// else outB (bf16) / outF (fp32).
// ---------------------------------------------------------------------------
template <int BMT, int BNT>
__global__ __launch_bounds__(256) void mfma_gemm_kernel(
    int Kd,
    const unsigned short* __restrict__ A, int lda,
    const unsigned short* __restrict__ Wt, int ldw,
    const float* __restrict__ bias,
    float* __restrict__ outF, unsigned short* __restrict__ outB, int ldo,
    const float* __restrict__ qf, const int* __restrict__ zstate,
    unsigned short* __restrict__ xb_epi, unsigned short* __restrict__ bern_epi,
    int layer) {
  constexpr int MF  = BMT / 32;            // m-fragments per wave
  constexpr int NF  = BNT / 32;            // n-fragments per wave
  constexpr int ACH = BMT / 16;            // A stage-chunks
  constexpr int TCH = ACH + BNT / 16;      // total chunks
  constexpr int CPW = TCH / 4;             // chunks per wave (2, 3 or 4)
  __shared__ __align__(16) unsigned short Asl[4][BMT * 32];
  __shared__ __align__(16) unsigned short Bsl[4][BNT * 32];
  const int t    = threadIdx.x;
  const int lane = t & 63;
  const int wid  = t >> 6;
  const int wr   = wid >> 1, wc = wid & 1;

  const int gx  = gridDim.x;
  const int nwg = gx * gridDim.y;
  int bid = blockIdx.y * gx + blockIdx.x;
  if ((nwg & 7) == 0) bid = (bid & 7) * (nwg >> 3) + (bid >> 3);
  const int row0 = (bid / gx) * BMT;
  const int col0 = (bid % gx) * BNT;

  f32x4 acc[MF][NF] = {};

  const int swz    = ((lane & 3) ^ ((lane >> 3) & 3)) * 8;
  const int subrow = lane >> 2;
  const int fr = lane & 15;
  const int fq = lane >> 4;

  const int nkt = Kd >> 5;

  auto stage = [&](int kt, int pb) {
    const int kbase = kt << 5;
#pragma unroll
    for (int i = 0; i < CPW; ++i) {
      const int c = wid * CPW + i;               // < ACH = A chunk, else B
      if (c < ACH) {
        const int r = row0 + c * 16 + subrow;
        gload16(A + (size_t)r * lda + kbase + swz, &Asl[pb][c * 512]);
      } else {
        const int cc = c - ACH;
        const int r = col0 + cc * 16 + subrow;
        gload16(Wt + (size_t)r * ldw + kbase + swz, &Bsl[pb][cc * 512]);
      }
    }
  };

  stage(0, 0);
  if (nkt > 1) stage(1, 1);

  for (int kt = 0; kt < nkt; ++kt) {
    const int pb = kt & 3;
    if (kt + 2 < nkt) {
      stage(kt + 2, (kt + 2) & 3);
      if constexpr (CPW == 2)
        asm volatile("s_waitcnt vmcnt(4)" ::: "memory");
      else if constexpr (CPW == 3)
        asm volatile("s_waitcnt vmcnt(6)" ::: "memory");
      else
        asm volatile("s_waitcnt vmcnt(8)" ::: "memory");
    } else if (kt + 1 < nkt) {
      if constexpr (CPW == 2)
        asm volatile("s_waitcnt vmcnt(2)" ::: "memory");
      else if constexpr (CPW == 3)
        asm volatile("s_waitcnt vmcnt(3)" ::: "memory");
      else
        asm volatile("s_waitcnt vmcnt(4)" ::: "memory");
    } else {
      asm volatile("s_waitcnt vmcnt(0)" ::: "memory");
    }
    __builtin_amdgcn_s_barrier();
    asm volatile("" ::: "memory");

    short8 af[MF], bfr[NF];
#pragma unroll
    for (int m = 0; m < MF; ++m) {
      const int r = wr * (MF * 16) + m * 16 + fr;
      const int colb = (fq * 16) ^ (((r >> 1) & 3) << 4);
      af[m] = *(const short8*)((const char*)&Asl[pb][0] + r * 64 + colb);
    }
#pragma unroll
    for (int n = 0; n < NF; ++n) {
      const int r = wc * (NF * 16) + n * 16 + fr;
      const int colb = (fq * 16) ^ (((r >> 1) & 3) << 4);
      bfr[n] = *(const short8*)((const char*)&Bsl[pb][0] + r * 64 + colb);
    }
    __builtin_amdgcn_s_setprio(1);
#pragma unroll
    for (int m = 0; m < MF; ++m)
#pragma unroll
      for (int n = 0; n < NF; ++n)
        acc[m][n] = __builtin_amdgcn_mfma_f32_16x16x32_bf16(af[m], bfr[n],
                                                            acc[m][n], 0, 0, 0);
    __builtin_amdgcn_s_setprio(0);
  }

  // epilogue: C/D layout col = lane&15, row = (lane>>4)*4 + reg
  int fastepi = 0; float q0 = 0.f;
  if (xb_epi) { fastepi = zstate[1]; q0 = qf[0]; }
#pragma unroll
  for (int n = 0; n < NF; ++n) {
    const int col = col0 + wc * (NF * 16) + n * 16 + fr;
    const float bv = bias[col];
#pragma unroll
    for (int m = 0; m < MF; ++m) {
      const int rbase = row0 + wr * (MF * 16) + m * 16 + fq * 4;
#pragma unroll
      for (int r = 0; r < 4; ++r) {
        const float v = acc[m][n][r] + bv;
        const size_t rr = (size_t)(rbase + r);
        if (fastepi) {
          const float hv = fmaxf(q0 * v, 0.f);
          const unsigned short hb = f2bf(hv);
          xb_epi[rr * XBW + 768 + layer * HD + col] = hb;
          if (bern_epi)
            bern_epi[rr * 768 + layer * HD + col] =
                f2bf(bf2f(hb) + bf2f(xb_epi[rr * XBW + layer * HD + col]));
        } else if (outB) {
          outB[rr * ldo + col] = f2bf(v);
        } else {
          outF[rr * ldo + col] = v;
        }
      }
    }
  }
}

// ---------------------------------------------------------------------------
// Fused Horner: all K+1 steps for one (graph, 4-channel slab) in one block.
// fused && zstate[1]: GEMM epilogue already did the work -> immediate exit.
// General path: acc ping-pong in LDS, dis/cnt staged, zstate skipping.
// ---------------------------------------------------------------------------
__global__ __launch_bounds__(256, 1) void horner_kernel(
    const unsigned short* __restrict__ h,        // [NROWS][HD] bf16 pre-act
    const int* __restrict__ cnt, const float* __restrict__ dis,
    const unsigned short* __restrict__ colidx,
    const float* __restrict__ qf, const int* __restrict__ zstate,
    unsigned short* __restrict__ XB, unsigned short* __restrict__ bern,
    int layer, int fused) {
  __shared__ float accA[NB * 4];
  __shared__ float accB[NB * 4];
  __shared__ float dls[NB];
  __shared__ int   cls[NB];
  const int blk = blockIdx.x;                    // 512 = 8 graphs * 64 slabs
  const int b   = blk >> 6;
  const int ch0 = (blk & 63) * 4;
  const int t   = threadIdx.x;
  const size_t rowbase = (size_t)b * NB;

  if (zstate[1]) {
    if (fused) return;                           // epilogue already did it
    const float q0 = qf[0];
    for (int r = t; r < NB; r += 256) {
      union { unsigned short s[4]; uint2 u; } iv, ov, xv, bv;
      iv.u = *(const uint2*)&h[(rowbase + r) * HD + ch0];
#pragma unroll
      for (int j = 0; j < 4; ++j)
        ov.s[j] = f2bf(fmaxf(q0 * bf2f(iv.s[j]), 0.f));
      *(uint2*)&XB[(rowbase + r) * XBW + 768 + layer * HD + ch0] = ov.u;
      if (bern) {
        xv.u = *(const uint2*)&XB[(rowbase + r) * XBW + layer * HD + ch0];
#pragma unroll
        for (int j = 0; j < 4; ++j)
          bv.s[j] = f2bf(bf2f(ov.s[j]) + bf2f(xv.s[j]));
        *(uint2*)&bern[(rowbase + r) * 768 + layer * HD + ch0] = bv.u;
      }
    }
    return;
  }

  for (int r = t; r < NB; r += 256) {
    dls[r] = dis[rowbase + r];
    cls[r] = cnt[rowbase + r];
  }
  __syncthreads();
  float* cur = accA;
  float* nxt = accB;
  const int ch = t & 3;
  for (int m = KORD; m >= 0; --m) {
    if (m == 0 || !zstate[m]) {
      const float qm = qf[m];
      const int gather = !zstate[m + 1];
      for (int r = t >> 2; r < NB; r += 64) {
        float s = 0.f;
        if (gather) {
          const int deg = cls[r];
          const float di = dls[r];
          const unsigned short* ci = colidx + (rowbase + r) * MAXDEG;
          for (int e = 0; e < deg; ++e) {
            const int nb = ci[e];
            s += di * dls[nb] * cur[nb * 4 + ch];
          }
        }
        if (qm != 0.f) s += qm * bf2f(h[(rowbase + r) * HD + ch0 + ch]);
        if (m == 0) {
          const float hv = fmaxf(s, 0.f);
          XB[(rowbase + r) * XBW + 768 + layer * HD + ch0 + ch] = f2bf(hv);
          if (bern)
            bern[(rowbase + r) * 768 + layer * HD + ch0 + ch] = f2bf(
                hv + bf2f(XB[(rowbase + r) * XBW + layer * HD + ch0 + ch]));
        } else {
          nxt[r * 4 + ch] = s;
        }
      }
    }
    __syncthreads();
    float* tp = cur; cur = nxt; nxt = tp;
  }
}

// ---------------------------------------------------------------------------
extern "C" void kernel_launch(void* const* d_in, const int* in_sizes, int n_in,
                              void* d_out, int out_size, void* d_ws, size_t ws_size,
                              hipStream_t stream) {
  const float* adj  = (const float*)d_in[0];
  const float* x    = (const float*)d_in[1];
  const float* coe  = (const float*)d_in[2];
  const float* W0   = (const float*)d_in[3];
  const float* b0   = (const float*)d_in[4];
  const float* W1   = (const float*)d_in[5];
  const float* b1   = (const float*)d_in[6];
  const float* W2   = (const float*)d_in[7];
  const float* b2   = (const float*)d_in[8];
  const float* Wout = (const float*)d_in[9];
  const float* bout = (const float*)d_in[10];
  float* outp = (float*)d_out;

  // bufH (GEMM output when the general Horner path is live, bf16) lives in
  // d_out; dead by the time the final GEMM overwrites d_out.
  unsigned short* bufH = (unsigned short*)outp;

  char* ws = (char*)d_ws;
  size_t off = 0;
  float* qf     = (float*)(ws + off); off += 256;
  int*   zstate = (int*)(ws + off);   off += 256;
  int*   cnt    = (int*)(ws + off);   off += 65536;
  float* dis    = (float*)(ws + off); off += 65536;
  unsigned short* colidx = (unsigned short*)(ws + off); off += (size_t)NROWS * MAXDEG * 2;
  unsigned short* XB     = (unsigned short*)(ws + off); off += (size_t)NROWS * XBW * 2;
  unsigned short* Wt0 = (unsigned short*)(ws + off); off += (size_t)256 * 768 * 2;
  unsigned short* Wt1 = (unsigned short*)(ws + off); off += (size_t)256 * 1024 * 2;
  unsigned short* Wt2 = (unsigned short*)(ws + off); off += (size_t)256 * 1280 * 2;
  unsigned short* WtO = (unsigned short*)(ws + off); off += (size_t)768 * 1536 * 2;
  unsigned short* bern = (unsigned short*)(ws + off);
  const size_t need = off + (size_t)NROWS * 768 * 2;   // ~77.9 MB
  const int split = ws_size >= need;                   // bern fits in ws?
  unsigned short* bernp = split ? bern : (unsigned short*)nullptr;

  hipLaunchKernelGGL(qz_kernel, dim3(1), dim3(128), 0, stream, coe, qf, zstate);
  hipLaunchKernelGGL(prep_kernel, dim3(8064), dim3(256), 0, stream,
                     adj, x, W0, W1, W2, Wout, zstate,
                     cnt, dis, colidx, XB, Wt0, Wt1, Wt2, WtO);

  // layer l: h = [x|h0|..] @ Wl + bl (bf16 MFMA 64x64 tiles, 1024 blocks =
  // 4/CU, fast-Horner fused in epilogue when zstate[1]); Horner early-exits.
  auto layer = [&](int Kd, const unsigned short* Wt, const float* bias, int l) {
    hipLaunchKernelGGL((mfma_gemm_kernel<64, 64>), dim3(4, 256), dim3(256), 0,
                       stream, Kd, XB, XBW, Wt, Kd, bias,
                       (float*)nullptr, bufH, HD, qf, zstate, XB, bernp, l);
    hipLaunchKernelGGL(horner_kernel, dim3(512), dim3(256), 0, stream,
                       bufH, cnt, dis, colidx, qf, zstate, XB, bernp, l, 1);
  };
  layer(768,  Wt0, b0, 0);
  layer(1024, Wt1, b1, 1);
  layer(1280, Wt2, b2, 2);

  // out = bern @ Wout + bout (split: K=768 on materialized bern)
  //     = [x | h0h1h2] @ [Wout ; Wout] + bout (fallback: K=1536 dup)
  if (split)
    hipLaunchKernelGGL((mfma_gemm_kernel<64, 128>), dim3(6, 256), dim3(256), 0,
                       stream, 768, bern, 768, WtO, 1536, bout,
                       outp, (unsigned short*)nullptr, 768,
                       qf, zstate, (unsigned short*)nullptr,
                       (unsigned short*)nullptr, 0);
  else
    hipLaunchKernelGGL((mfma_gemm_kernel<64, 128>), dim3(6, 256), dim3(256), 0,
                       stream, 1536, XB, XBW, WtO, 1536, bout,
                       outp, (unsigned short*)nullptr, 768,
                       qf, zstate, (unsigned short*)nullptr,
                       (unsigned short*)nullptr, 0);
}